// Round 9
// baseline (941.412 us; speedup 1.0000x reference)
//
#include <hip/hip_runtime.h>
#include <hip/hip_bf16.h>
#include <float.h>

// Problem constants
#define BB 8
#define NN 4096
#define KNN 16
#define Dh 128
#define NPTS (BB*NN)          // 32768
#define NPART 8               // kNN candidate partitions
#define PARTSZ (NN/NPART)     // 512

typedef __attribute__((ext_vector_type(8))) short bf16x8;   // 8 bf16 = 4 VGPRs
typedef __attribute__((ext_vector_type(8))) unsigned short u16x8;
typedef __attribute__((ext_vector_type(4))) float f32x4;    // MFMA 16x16 accumulator

#define MFMA16(a,b,c) __builtin_amdgcn_mfma_f32_16x16x32_bf16(a,b,c,0,0,0)

__device__ __forceinline__ unsigned short f2b(float f) {   // native RNE cvt
  __hip_bfloat16 h = __float2bfloat16(f);
  return *(unsigned short*)&h;
}
__device__ __forceinline__ unsigned pack_bf2(float lo, float hi) {
  __hip_bfloat16 l = __float2bfloat16(lo), h = __float2bfloat16(hi);
  return (unsigned)(*(unsigned short*)&l) | ((unsigned)(*(unsigned short*)&h) << 16);
}
__device__ __forceinline__ float b2f(unsigned short s) {
  union { unsigned u; float f; } v; v.u = ((unsigned)s) << 16; return v.f;
}
__device__ __forceinline__ float blo(unsigned u) {        // low bf16 of packed kv
  union { unsigned u; float f; } v; v.u = u << 16; return v.f;
}
__device__ __forceinline__ float bhi(unsigned u) {        // high bf16 of packed kv
  union { unsigned u; float f; } v; v.u = u & 0xffff0000u; return v.f;
}
__device__ __forceinline__ int swz16(int row) { return (row >> 2) << 4; } // trans-tile XOR

// ---------------------------------------------------------------------------
// x = relu(features @ W_embed)   [B*N,3] @ [3,128], f32 out
__global__ __launch_bounds__(256) void embed_kernel(
    const float* __restrict__ f, const float* __restrict__ We, float* __restrict__ x) {
  int i = blockIdx.x * 256 + threadIdx.x;
  if (i >= NPTS * Dh) return;
  int p = i >> 7, d = i & 127;
  float f0 = f[p*3+0], f1 = f[p*3+1], f2 = f[p*3+2];
  float v = f0 * We[0*Dh + d] + f1 * We[1*Dh + d] + f2 * We[2*Dh + d];
  x[i] = fmaxf(v, 0.f);
}

// ---------------------------------------------------------------------------
// kNN stage 1: per-partition top-16 with buffered-drain insert batching.
__global__ __launch_bounds__(256) void knn_part_kernel(
    const float* __restrict__ pos, unsigned short* __restrict__ pidx) {
  __shared__ float4 cand[PARTSZ];     // 8 KB
  int b = blockIdx.z, part = blockIdx.y;
  const float* pb = pos + (size_t)b * NN * 3;
  int c0 = part * PARTSZ;
  for (int i = threadIdx.x; i < PARTSZ; i += 256) {
    float X = pb[(c0+i)*3+0], Y = pb[(c0+i)*3+1], Z = pb[(c0+i)*3+2];
    cand[i] = make_float4(X, Y, Z, X*X + Y*Y + Z*Z);
  }
  __syncthreads();

  int q = blockIdx.x * 256 + threadIdx.x;
  float qx = pb[q*3+0], qy = pb[q*3+1], qz = pb[q*3+2];
  float qs = qx*qx + qy*qy + qz*qz;

  float val[KNN]; int ind[KNN];
  float cmax; int cslot;

  #pragma unroll
  for (int t = 0; t < KNN; t++) {
    float4 c = cand[t];
    val[t] = qs + c.w - 2.f*(qx*c.x + qy*c.y + qz*c.z);
    ind[t] = t;
  }
  cmax = val[0]; cslot = 0;
  #pragma unroll
  for (int i = 1; i < KNN; i++)
    if (val[i] >= cmax) { cmax = val[i]; cslot = i; }   // evict latest among ties

  float bv0 = 0.f, bv1 = 0.f, bv2 = 0.f, bv3 = 0.f;
  int   bi0 = 0,   bi1 = 0,   bi2 = 0,   bi3 = 0;
  int   cnt = 0;

#define DRAIN_SLOT(S, BV, BI)                                      \
  { bool act = ((S) < cnt) && ((BV) < cmax);                       \
    if (__ballot(act)) {                                           \
      _Pragma("unroll")                                            \
      for (int i = 0; i < KNN; i++) {                              \
        bool r = act && (i == cslot);                              \
        val[i] = r ? (BV) : val[i];                                \
        ind[i] = r ? (BI) : ind[i];                                \
      }                                                            \
      cmax = val[0]; cslot = 0;                                    \
      _Pragma("unroll")                                            \
      for (int i = 1; i < KNN; i++)                                \
        if (val[i] >= cmax) { cmax = val[i]; cslot = i; }          \
    } }
#define DRAIN_ALL                                                  \
  { DRAIN_SLOT(0, bv0, bi0) DRAIN_SLOT(1, bv1, bi1)                \
    DRAIN_SLOT(2, bv2, bi2) DRAIN_SLOT(3, bv3, bi3) cnt = 0; }

  for (int m = KNN; m < PARTSZ; m++) {
    float4 c = cand[m];
    float d2 = qs + c.w - 2.f*(qx*c.x + qy*c.y + qz*c.z);
    if (d2 < cmax) {
      bv0 = (cnt == 0) ? d2 : bv0;  bi0 = (cnt == 0) ? m : bi0;
      bv1 = (cnt == 1) ? d2 : bv1;  bi1 = (cnt == 1) ? m : bi1;
      bv2 = (cnt == 2) ? d2 : bv2;  bi2 = (cnt == 2) ? m : bi2;
      bv3 = (cnt == 3) ? d2 : bv3;  bi3 = (cnt == 3) ? m : bi3;
      cnt++;
    }
    if (__ballot(cnt == 4)) DRAIN_ALL
  }
  if (__ballot(cnt > 0)) DRAIN_ALL

#undef DRAIN_SLOT
#undef DRAIN_ALL

  size_t base = ((size_t)(b*NN + q) * NPART + part) * KNN;
  #pragma unroll
  for (int i = 0; i < KNN; i++) pidx[base + i] = (unsigned short)(b*NN + c0 + ind[i]);
}

// ---------------------------------------------------------------------------
// kNN stage 2: merge 8 partial top-16 lists -> final top-16.
__global__ __launch_bounds__(256) void knn_merge_kernel(
    const float* __restrict__ pos, const unsigned short* __restrict__ pidx,
    unsigned short* __restrict__ idxout) {
  int p = blockIdx.x * 256 + threadIdx.x;
  float qx = pos[p*3+0], qy = pos[p*3+1], qz = pos[p*3+2];
  float qs = qx*qx + qy*qy + qz*qz;

  float val[KNN]; int ind[KNN];
  #pragma unroll
  for (int i = 0; i < KNN; i++) { val[i] = FLT_MAX; ind[i] = 0; }
  float cmax = FLT_MAX; int cslot = 0;

  for (int t = 0; t < NPART*KNN; t++) {
    int j = pidx[(size_t)p*NPART*KNN + t];
    float X = pos[j*3+0], Y = pos[j*3+1], Z = pos[j*3+2];
    float sq = X*X + Y*Y + Z*Z;
    float d2 = qs + sq - 2.f*(qx*X + qy*Y + qz*Z);
    if (d2 < cmax) {
      #pragma unroll
      for (int i = 0; i < KNN; i++) if (i == cslot) { val[i] = d2; ind[i] = j; }
      cmax = val[0]; cslot = 0;
      #pragma unroll
      for (int i = 1; i < KNN; i++) if (val[i] >= cmax) { cmax = val[i]; cslot = i; }
    }
  }
  #pragma unroll
  for (int i = 0; i < KNN; i++) idxout[(size_t)p*KNN + i] = (unsigned short)ind[i];
}

// ---------------------------------------------------------------------------
// Weight prep: WT[z][l][o][i] = bf16(W[z][l][i][o])
__global__ __launch_bounds__(256) void wprep_all_kernel(
    const float* __restrict__ W0, const float* __restrict__ W1,
    const float* __restrict__ W2, const float* __restrict__ W3,
    const float* __restrict__ W4, const float* __restrict__ W5,
    const float* __restrict__ W6, unsigned short* __restrict__ wT) {
  const float* srcs[7] = {W0, W1, W2, W3, W4, W5, W6};
  int z = blockIdx.z, m = blockIdx.y;
  const float* W = srcs[z] + m*16384;
  unsigned short* WT = wT + z*32768 + m*16384;
  int t = blockIdx.x * 256 + threadIdx.x;
  int o = t >> 7, i = t & 127;
  WT[o*128 + i] = f2b(W[i*128 + o]);
}

// ---------------------------------------------------------------------------
// q / packed kv = x @ {Wq, Wk|Wv}. kv: u32 = {k lo16, v hi16} per (row,ch).
__global__ __launch_bounds__(256) void qkv_kernel(
    const float* __restrict__ x,
    const unsigned short* __restrict__ QT, const unsigned short* __restrict__ KT,
    const unsigned short* __restrict__ VT,
    unsigned short* __restrict__ qb, unsigned* __restrict__ kvb) {
  int w = threadIdx.x >> 6, l = threadIdx.x & 63;
  int lr = l & 15, lg = l >> 4;
  int R = blockIdx.x * 64 + w * 16;
  const float* xr = x + (size_t)(R + lr) * Dh + lg * 8;
  bf16x8 a[4];
  #pragma unroll
  for (int kt = 0; kt < 4; kt++) {
    bf16x8 av;
    #pragma unroll
    for (int j = 0; j < 8; j++) av[j] = (short)f2b(xr[kt*32 + j]);
    a[kt] = av;
  }
  #pragma unroll
  for (int n = 0; n < 8; n++) {
    f32x4 c = {0.f, 0.f, 0.f, 0.f};
    #pragma unroll
    for (int kt = 0; kt < 4; kt++)
      c = MFMA16(a[kt], *(const bf16x8*)&QT[(n*16 + lr)*Dh + kt*32 + lg*8], c);
    #pragma unroll
    for (int r = 0; r < 4; r++)
      qb[(size_t)(R + lg*4 + r)*Dh + n*16 + lr] = f2b(c[r]);
  }
  #pragma unroll
  for (int n = 0; n < 8; n++) {
    f32x4 ck = {0.f, 0.f, 0.f, 0.f}, cv = {0.f, 0.f, 0.f, 0.f};
    #pragma unroll
    for (int kt = 0; kt < 4; kt++) {
      ck = MFMA16(a[kt], *(const bf16x8*)&KT[(n*16 + lr)*Dh + kt*32 + lg*8], ck);
      cv = MFMA16(a[kt], *(const bf16x8*)&VT[(n*16 + lr)*Dh + kt*32 + lg*8], cv);
    }
    #pragma unroll
    for (int r = 0; r < 4; r++)
      kvb[(size_t)(R + lg*4 + r)*Dh + n*16 + lr] = pack_bf2(ck[r], cv[r]);
  }
}

// ---------------------------------------------------------------------------
// per-point prefetch context (registers only)
struct PtCtx {
  int jA, jC[4];
  float rx, ry, rz;
  unsigned short qv[8];
};
__device__ __forceinline__ void load_ctx(PtCtx& c, int p,
    const unsigned short* __restrict__ idxb, const float* __restrict__ pos,
    const unsigned short* __restrict__ qb, int lr, int lg) {
  c.jA = idxb[(size_t)p*KNN + lr];
  #pragma unroll
  for (int r = 0; r < 4; r++) c.jC[r] = idxb[(size_t)p*KNN + lg*4 + r];
  float px0 = pos[p*3+0], py0 = pos[p*3+1], pz0 = pos[p*3+2];
  c.rx = px0 - pos[c.jA*3+0];
  c.ry = py0 - pos[c.jA*3+1];
  c.rz = pz0 - pos[c.jA*3+2];
  #pragma unroll
  for (int n = 0; n < 8; n++) c.qv[n] = qb[(size_t)p*Dh + n*16 + lr];
}

// ---------------------------------------------------------------------------
// Mega fused vector-attention block. 256 blocks (1/CU) x 512 thr (8 waves).
// XCD-swizzled so all 32 blocks of one batch land on one XCD (kvb slice 2 MB
// fits 4 MB per-XCD L2). waves_per_eu(2,2): LDS already caps occupancy at
// 2 waves/SIMD; the RANGE form (max=2) makes the register allocator TARGET
// that occupancy, unlocking 256 VGPRs so the kv burst + ctx prefetch stay
// in registers (rounds 6/8 spilled ~18 regs/point at the 128-VGPR target).
__global__ void __attribute__((amdgpu_flat_work_group_size(512, 512)))
__attribute__((amdgpu_waves_per_eu(2, 2)))
fused_mega_kernel(
    const unsigned short* __restrict__ qb, const unsigned* __restrict__ kvb,
    const unsigned short* __restrict__ idxb, const float* __restrict__ pos,
    const float* __restrict__ P1,
    const unsigned short* __restrict__ P2T, const unsigned short* __restrict__ G1T,
    const unsigned short* __restrict__ G2T, unsigned short* __restrict__ aggb) {
  __shared__ __align__(16) unsigned short wB[3][16384];    // 96 KB, swizzled
  __shared__ __align__(16) unsigned short trans[8][2048];  // 32 KB (4 KB/wave)
  int tid = threadIdx.x;
  int wv = tid >> 6, l = tid & 63;
  int lr = l & 15, lg = l >> 4;
  const int swz = (lr & 7) << 3;        // weight-LDS read swizzle (u16)
  const int swtR = swz16(lr);           // trans-tile read swizzle (row=lr)

  // XCD swizzle: hardware XCD = blockIdx.x % 8. Map so batch b's 32 blocks
  // all have blockIdx.x % 8 == b.
  int orig = (blockIdx.x & 7) * 32 + (blockIdx.x >> 3);

  {
    const unsigned short* srcs[3] = {P2T, G1T, G2T};
    #pragma unroll
    for (int z = 0; z < 3; z++) {
      const unsigned short* src = srcs[z];
      for (int t = tid * 8; t < 16384; t += 512 * 8) {
        int dst = t ^ (((t >> 7) & 7) << 3);
        *(u16x8*)&wB[z][dst] = *(const u16x8*)&src[t];
      }
    }
  }
  __syncthreads();

  unsigned short* tb = trans[wv];
  int p0 = orig * 128 + wv * 16;

  PtCtx cur, nxt;
  load_ctx(cur, p0, idxb, pos, qb, lr, lg);
  nxt = cur;

  #pragma unroll 1
  for (int i = 0; i < 16; i++) {
    int p = p0 + i;

    // ---- burst-issue all 32 packed kv gathers for THIS point (used later)
    const unsigned* kvp0 = kvb + (size_t)cur.jC[0]*Dh;
    const unsigned* kvp1 = kvb + (size_t)cur.jC[1]*Dh;
    const unsigned* kvp2 = kvb + (size_t)cur.jC[2]*Dh;
    const unsigned* kvp3 = kvb + (size_t)cur.jC[3]*Dh;
    unsigned kvr[8][4];
    #pragma unroll
    for (int n = 0; n < 8; n++) {
      kvr[n][0] = kvp0[n*16 + lr];
      kvr[n][1] = kvp1[n*16 + lr];
      kvr[n][2] = kvp2[n*16 + lr];
      kvr[n][3] = kvp3[n*16 + lr];
    }

    // ---- prefetch next point's ctx (consumed next iteration)
    if (i < 15) load_ctx(nxt, p + 1, idxb, pos, qb, lr, lg);

    // ---- t1 = relu(rel @ P1) in A-frag layout; float4 P1 loads (L1-hot)
    bf16x8 aT[4];
    #pragma unroll
    for (int kt = 0; kt < 4; kt++) {
      int c0 = kt*32 + lg*8;
      float4 pa0 = *(const float4*)&P1[c0],        pa1 = *(const float4*)&P1[c0+4];
      float4 pb0 = *(const float4*)&P1[Dh+c0],     pb1 = *(const float4*)&P1[Dh+c0+4];
      float4 pc0 = *(const float4*)&P1[2*Dh+c0],   pc1 = *(const float4*)&P1[2*Dh+c0+4];
      bf16x8 av;
      av[0] = (short)f2b(fmaxf(cur.rx*pa0.x + cur.ry*pb0.x + cur.rz*pc0.x, 0.f));
      av[1] = (short)f2b(fmaxf(cur.rx*pa0.y + cur.ry*pb0.y + cur.rz*pc0.y, 0.f));
      av[2] = (short)f2b(fmaxf(cur.rx*pa0.z + cur.ry*pb0.z + cur.rz*pc0.z, 0.f));
      av[3] = (short)f2b(fmaxf(cur.rx*pa0.w + cur.ry*pb0.w + cur.rz*pc0.w, 0.f));
      av[4] = (short)f2b(fmaxf(cur.rx*pa1.x + cur.ry*pb1.x + cur.rz*pc1.x, 0.f));
      av[5] = (short)f2b(fmaxf(cur.rx*pa1.y + cur.ry*pb1.y + cur.rz*pc1.y, 0.f));
      av[6] = (short)f2b(fmaxf(cur.rx*pa1.z + cur.ry*pb1.z + cur.rz*pc1.z, 0.f));
      av[7] = (short)f2b(fmaxf(cur.rx*pa1.w + cur.ry*pb1.w + cur.rz*pc1.w, 0.f));
      aT[kt] = av;
    }

    // ---- DELTA = t1 @ P2 (C-layout regs, f32)
    f32x4 dlt[8];
    #pragma unroll
    for (int n = 0; n < 8; n++) {
      f32x4 c = {0.f, 0.f, 0.f, 0.f};
      #pragma unroll
      for (int kt = 0; kt < 4; kt++)
        c = MFMA16(aT[kt], *(const bf16x8*)&wB[0][((n*16 + lr)*Dh + kt*32 + lg*8) ^ swz], c);
      dlt[n] = c;
    }

    // ---- g = q - kj + delta -> swizzled trans tile (C-layout scatter)
    #pragma unroll
    for (int n = 0; n < 8; n++) {
      float q = b2f(cur.qv[n]);
      #pragma unroll
      for (int r = 0; r < 4; r++) {
        int row = lg*4 + r, ch = n*16 + lr;
        tb[(row*Dh + ch) ^ swz16(row)] = f2b(q - blo(kvr[n][r]) + dlt[n][r]);
      }
    }

    // ---- H = relu(g @ G1)
    bf16x8 ag[4];
    #pragma unroll
    for (int kt = 0; kt < 4; kt++)
      ag[kt] = *(const bf16x8*)&tb[(lr*Dh + kt*32 + lg*8) ^ swtR];
    f32x4 hh[8];
    #pragma unroll
    for (int n = 0; n < 8; n++) {
      f32x4 c = {0.f, 0.f, 0.f, 0.f};
      #pragma unroll
      for (int kt = 0; kt < 4; kt++)
        c = MFMA16(ag[kt], *(const bf16x8*)&wB[1][((n*16 + lr)*Dh + kt*32 + lg*8) ^ swz], c);
      hh[n] = c;
    }
    #pragma unroll
    for (int n = 0; n < 8; n++) {
      #pragma unroll
      for (int r = 0; r < 4; r++) {
        int row = lg*4 + r, ch = n*16 + lr;
        tb[(row*Dh + ch) ^ swz16(row)] = f2b(fmaxf(hh[n][r], 0.f));
      }
    }

    // ---- LOGITS = H @ G2
    bf16x8 ah[4];
    #pragma unroll
    for (int kt = 0; kt < 4; kt++)
      ah[kt] = *(const bf16x8*)&tb[(lr*Dh + kt*32 + lg*8) ^ swtR];
    f32x4 lgt[8];
    #pragma unroll
    for (int n = 0; n < 8; n++) {
      f32x4 c = {0.f, 0.f, 0.f, 0.f};
      #pragma unroll
      for (int kt = 0; kt < 4; kt++)
        c = MFMA16(ah[kt], *(const bf16x8*)&wB[2][((n*16 + lr)*Dh + kt*32 + lg*8) ^ swz], c);
      lgt[n] = c;
    }

    // ---- softmax over 16 neighbors + agg = sum attn*(v+delta)
    #pragma unroll
    for (int n = 0; n < 8; n++) {
      f32x4 L = lgt[n];
      float m = fmaxf(fmaxf(L[0], L[1]), fmaxf(L[2], L[3]));
      m = fmaxf(m, __shfl_xor(m, 16));
      m = fmaxf(m, __shfl_xor(m, 32));
      float e0 = __expf(L[0]-m), e1 = __expf(L[1]-m);
      float e2 = __expf(L[2]-m), e3 = __expf(L[3]-m);
      float s = e0 + e1 + e2 + e3;
      s += __shfl_xor(s, 16);
      s += __shfl_xor(s, 32);
      float inv = 1.f / s;
      float ws;
      ws  = e0 * (bhi(kvr[n][0]) + dlt[n][0]);
      ws += e1 * (bhi(kvr[n][1]) + dlt[n][1]);
      ws += e2 * (bhi(kvr[n][2]) + dlt[n][2]);
      ws += e3 * (bhi(kvr[n][3]) + dlt[n][3]);
      ws *= inv;
      ws += __shfl_xor(ws, 16);
      ws += __shfl_xor(ws, 32);
      if (lg == 0) aggb[(size_t)p*Dh + n*16 + lr] = f2b(ws);
    }

    cur = nxt;
  }
}

// ---------------------------------------------------------------------------
// x += aggb @ Wo : [32768,128]@[128,128], f32 accumulate into x.
__global__ __launch_bounds__(256) void xupd_kernel(
    float* __restrict__ x, const unsigned short* __restrict__ aggb,
    const unsigned short* __restrict__ WoT) {
  int w = threadIdx.x >> 6, l = threadIdx.x & 63;
  int lr = l & 15, lg = l >> 4;
  int R = blockIdx.x * 64 + w * 16;
  bf16x8 a[4];
  #pragma unroll
  for (int kt = 0; kt < 4; kt++)
    a[kt] = *(const bf16x8*)&aggb[(size_t)(R + lr)*Dh + kt*32 + lg*8];
  #pragma unroll
  for (int n = 0; n < 8; n++) {
    f32x4 c = {0.f, 0.f, 0.f, 0.f};
    #pragma unroll
    for (int kt = 0; kt < 4; kt++)
      c = MFMA16(a[kt], *(const bf16x8*)&WoT[(n*16 + lr)*Dh + kt*32 + lg*8], c);
    #pragma unroll
    for (int r = 0; r < 4; r++)
      x[(size_t)(R + lg*4 + r)*Dh + n*16 + lr] += c[r];
  }
}

// ---------------------------------------------------------------------------
// Global max-pool + classifier head (f32)
__global__ __launch_bounds__(128) void pool_part_kernel(
    const float* __restrict__ x, float* __restrict__ part) {
  int b = blockIdx.y, chunk = blockIdx.x, d = threadIdx.x;
  const float* xb = x + ((size_t)b*NN + chunk*128) * Dh;
  float m = -FLT_MAX;
  for (int n = 0; n < 128; n++) m = fmaxf(m, xb[(size_t)n*Dh + d]);
  part[(b*32 + chunk)*Dh + d] = m;
}

__global__ __launch_bounds__(128) void head_kernel(
    const float* __restrict__ part, const float* __restrict__ W1,
    const float* __restrict__ W2, float* __restrict__ out) {
  int b = blockIdx.x, d = threadIdx.x;
  __shared__ float pooled[Dh], h[Dh];
  float m = -FLT_MAX;
  for (int c = 0; c < 32; c++) m = fmaxf(m, part[(b*32 + c)*Dh + d]);
  pooled[d] = m;
  __syncthreads();
  float acc = 0.f;
  for (int c = 0; c < Dh; c++) acc += pooled[c] * W1[c*Dh + d];
  h[d] = fmaxf(acc, 0.f);
  __syncthreads();
  if (d < 40) {
    float o = 0.f;
    for (int c = 0; c < Dh; c++) o += h[c] * W2[c*40 + d];
    out[b*40 + d] = o;
  }
}

// ---------------------------------------------------------------------------
extern "C" void kernel_launch(void* const* d_in, const int* in_sizes, int n_in,
                              void* d_out, int out_size, void* d_ws, size_t ws_size,
                              hipStream_t stream) {
  const float* features = (const float*)d_in[0];
  const float* pos      = (const float*)d_in[1];
  const float* W_embed  = (const float*)d_in[2];
  const float* Wq       = (const float*)d_in[3];
  const float* Wk       = (const float*)d_in[4];
  const float* Wv       = (const float*)d_in[5];
  const float* P1       = (const float*)d_in[6];
  const float* P2       = (const float*)d_in[7];
  const float* G1       = (const float*)d_in[8];
  const float* G2       = (const float*)d_in[9];
  const float* Wo       = (const float*)d_in[10];
  const float* Wc1      = (const float*)d_in[11];
  const float* Wc2      = (const float*)d_in[12];
  float* out = (float*)d_out;

  // workspace layout (16B-aligned slices)
  float* x = (float*)d_ws;                                     // NPTS*Dh f32 (16 MB)
  unsigned short* qb = (unsigned short*)(x + (size_t)NPTS*Dh); // NPTS*Dh bf16 (8 MB)
  unsigned* kvb = (unsigned*)(qb + (size_t)NPTS*Dh);           // NPTS*Dh u32 (16 MB)
  unsigned short* wT = (unsigned short*)(kvb + (size_t)NPTS*Dh); // 7*2*16384 bf16
  unsigned short* aggb = wT + 7*2*16384;                       // NPTS*Dh bf16 (8 MB)
  unsigned short* idxb = aggb + (size_t)NPTS*Dh;               // NPTS*KNN u16 (1 MB)

  // kNN partial indices (u16): aliased onto kvb (needs 8.4 MB of 16); dead before qkv.
  unsigned short* pidx = (unsigned short*)kvb;
  // pooled partials: aliased onto qb (dead after last fused layer).
  float* part = (float*)qb;

  unsigned short* QT  = wT + 0*32768;   // [2][128][128] each, transposed bf16
  unsigned short* KT  = wT + 1*32768;
  unsigned short* VT  = wT + 2*32768;
  unsigned short* P2T = wT + 3*32768;
  unsigned short* G1T = wT + 4*32768;
  unsigned short* G2T = wT + 5*32768;
  unsigned short* WoT = wT + 6*32768;

  knn_part_kernel<<<dim3(NN/256, NPART, BB), 256, 0, stream>>>(pos, pidx);
  knn_merge_kernel<<<NPTS/256, 256, 0, stream>>>(pos, pidx, idxb);

  wprep_all_kernel<<<dim3(64, 2, 7), 256, 0, stream>>>(Wq, Wk, Wv, P2, G1, G2, Wo, wT);
  embed_kernel<<<NPTS*Dh/256, 256, 0, stream>>>(features, W_embed, x);

  for (int l = 0; l < 2; l++) {
    qkv_kernel<<<NPTS/64, 256, 0, stream>>>(
        x, QT + l*16384, KT + l*16384, VT + l*16384, qb, kvb);
    fused_mega_kernel<<<256, 512, 0, stream>>>(
        qb, kvb, idxb, pos,
        P1 + l*3*Dh, P2T + l*16384, G1T + l*16384, G2T + l*16384, aggb);
    xupd_kernel<<<NPTS/64, 256, 0, stream>>>(x, aggb, WoT + l*16384);
  }

  pool_part_kernel<<<dim3(32, BB), 128, 0, stream>>>(x, part);
  head_kernel<<<BB, 128, 0, stream>>>(part, Wc1, Wc2, out);
}

// Round 10
// 870.902 us; speedup vs baseline: 1.0810x; 1.0810x over previous
//
#include <hip/hip_runtime.h>
#include <hip/hip_bf16.h>
#include <float.h>

// Problem constants
#define BB 8
#define NN 4096
#define KNN 16
#define Dh 128
#define NPTS (BB*NN)          // 32768
#define NPART 8               // kNN candidate partitions
#define PARTSZ (NN/NPART)     // 512

typedef __attribute__((ext_vector_type(8))) short bf16x8;   // 8 bf16 = 4 VGPRs
typedef __attribute__((ext_vector_type(8))) unsigned short u16x8;
typedef __attribute__((ext_vector_type(4))) float f32x4;    // MFMA 16x16 accumulator

#define MFMA16(a,b,c) __builtin_amdgcn_mfma_f32_16x16x32_bf16(a,b,c,0,0,0)

__device__ __forceinline__ unsigned short f2b(float f) {   // native RNE cvt
  __hip_bfloat16 h = __float2bfloat16(f);
  return *(unsigned short*)&h;
}
__device__ __forceinline__ unsigned pack_bf2(float lo, float hi) {
  __hip_bfloat16 l = __float2bfloat16(lo), h = __float2bfloat16(hi);
  return (unsigned)(*(unsigned short*)&l) | ((unsigned)(*(unsigned short*)&h) << 16);
}
__device__ __forceinline__ float b2f(unsigned short s) {
  union { unsigned u; float f; } v; v.u = ((unsigned)s) << 16; return v.f;
}
__device__ __forceinline__ float blo(unsigned u) {        // low bf16 of packed kv
  union { unsigned u; float f; } v; v.u = u << 16; return v.f;
}
__device__ __forceinline__ float bhi(unsigned u) {        // high bf16 of packed kv
  union { unsigned u; float f; } v; v.u = u & 0xffff0000u; return v.f;
}
__device__ __forceinline__ int swz16(int row) { return (row >> 2) << 4; } // trans-tile XOR

// ---------------------------------------------------------------------------
// x = relu(features @ W_embed)   [B*N,3] @ [3,128], f32 out
__global__ __launch_bounds__(256) void embed_kernel(
    const float* __restrict__ f, const float* __restrict__ We, float* __restrict__ x) {
  int i = blockIdx.x * 256 + threadIdx.x;
  if (i >= NPTS * Dh) return;
  int p = i >> 7, d = i & 127;
  float f0 = f[p*3+0], f1 = f[p*3+1], f2 = f[p*3+2];
  float v = f0 * We[0*Dh + d] + f1 * We[1*Dh + d] + f2 * We[2*Dh + d];
  x[i] = fmaxf(v, 0.f);
}

// ---------------------------------------------------------------------------
// kNN stage 1: per-partition top-16 with buffered-drain insert batching.
__global__ __launch_bounds__(256) void knn_part_kernel(
    const float* __restrict__ pos, unsigned short* __restrict__ pidx) {
  __shared__ float4 cand[PARTSZ];     // 8 KB
  int b = blockIdx.z, part = blockIdx.y;
  const float* pb = pos + (size_t)b * NN * 3;
  int c0 = part * PARTSZ;
  for (int i = threadIdx.x; i < PARTSZ; i += 256) {
    float X = pb[(c0+i)*3+0], Y = pb[(c0+i)*3+1], Z = pb[(c0+i)*3+2];
    cand[i] = make_float4(X, Y, Z, X*X + Y*Y + Z*Z);
  }
  __syncthreads();

  int q = blockIdx.x * 256 + threadIdx.x;
  float qx = pb[q*3+0], qy = pb[q*3+1], qz = pb[q*3+2];
  float qs = qx*qx + qy*qy + qz*qz;

  float val[KNN]; int ind[KNN];
  float cmax; int cslot;

  #pragma unroll
  for (int t = 0; t < KNN; t++) {
    float4 c = cand[t];
    val[t] = qs + c.w - 2.f*(qx*c.x + qy*c.y + qz*c.z);
    ind[t] = t;
  }
  cmax = val[0]; cslot = 0;
  #pragma unroll
  for (int i = 1; i < KNN; i++)
    if (val[i] >= cmax) { cmax = val[i]; cslot = i; }   // evict latest among ties

  float bv0 = 0.f, bv1 = 0.f, bv2 = 0.f, bv3 = 0.f;
  int   bi0 = 0,   bi1 = 0,   bi2 = 0,   bi3 = 0;
  int   cnt = 0;

#define DRAIN_SLOT(S, BV, BI)                                      \
  { bool act = ((S) < cnt) && ((BV) < cmax);                       \
    if (__ballot(act)) {                                           \
      _Pragma("unroll")                                            \
      for (int i = 0; i < KNN; i++) {                              \
        bool r = act && (i == cslot);                              \
        val[i] = r ? (BV) : val[i];                                \
        ind[i] = r ? (BI) : ind[i];                                \
      }                                                            \
      cmax = val[0]; cslot = 0;                                    \
      _Pragma("unroll")                                            \
      for (int i = 1; i < KNN; i++)                                \
        if (val[i] >= cmax) { cmax = val[i]; cslot = i; }          \
    } }
#define DRAIN_ALL                                                  \
  { DRAIN_SLOT(0, bv0, bi0) DRAIN_SLOT(1, bv1, bi1)                \
    DRAIN_SLOT(2, bv2, bi2) DRAIN_SLOT(3, bv3, bi3) cnt = 0; }

  for (int m = KNN; m < PARTSZ; m++) {
    float4 c = cand[m];
    float d2 = qs + c.w - 2.f*(qx*c.x + qy*c.y + qz*c.z);
    if (d2 < cmax) {
      bv0 = (cnt == 0) ? d2 : bv0;  bi0 = (cnt == 0) ? m : bi0;
      bv1 = (cnt == 1) ? d2 : bv1;  bi1 = (cnt == 1) ? m : bi1;
      bv2 = (cnt == 2) ? d2 : bv2;  bi2 = (cnt == 2) ? m : bi2;
      bv3 = (cnt == 3) ? d2 : bv3;  bi3 = (cnt == 3) ? m : bi3;
      cnt++;
    }
    if (__ballot(cnt == 4)) DRAIN_ALL
  }
  if (__ballot(cnt > 0)) DRAIN_ALL

#undef DRAIN_SLOT
#undef DRAIN_ALL

  size_t base = ((size_t)(b*NN + q) * NPART + part) * KNN;
  #pragma unroll
  for (int i = 0; i < KNN; i++) pidx[base + i] = (unsigned short)(b*NN + c0 + ind[i]);
}

// ---------------------------------------------------------------------------
// kNN stage 2: merge 8 partial top-16 lists -> final top-16.
__global__ __launch_bounds__(256) void knn_merge_kernel(
    const float* __restrict__ pos, const unsigned short* __restrict__ pidx,
    unsigned short* __restrict__ idxout) {
  int p = blockIdx.x * 256 + threadIdx.x;
  float qx = pos[p*3+0], qy = pos[p*3+1], qz = pos[p*3+2];
  float qs = qx*qx + qy*qy + qz*qz;

  float val[KNN]; int ind[KNN];
  #pragma unroll
  for (int i = 0; i < KNN; i++) { val[i] = FLT_MAX; ind[i] = 0; }
  float cmax = FLT_MAX; int cslot = 0;

  for (int t = 0; t < NPART*KNN; t++) {
    int j = pidx[(size_t)p*NPART*KNN + t];
    float X = pos[j*3+0], Y = pos[j*3+1], Z = pos[j*3+2];
    float sq = X*X + Y*Y + Z*Z;
    float d2 = qs + sq - 2.f*(qx*X + qy*Y + qz*Z);
    if (d2 < cmax) {
      #pragma unroll
      for (int i = 0; i < KNN; i++) if (i == cslot) { val[i] = d2; ind[i] = j; }
      cmax = val[0]; cslot = 0;
      #pragma unroll
      for (int i = 1; i < KNN; i++) if (val[i] >= cmax) { cmax = val[i]; cslot = i; }
    }
  }
  #pragma unroll
  for (int i = 0; i < KNN; i++) idxout[(size_t)p*KNN + i] = (unsigned short)ind[i];
}

// ---------------------------------------------------------------------------
// Weight prep: WT[z][l][o][i] = bf16(W[z][l][i][o])
__global__ __launch_bounds__(256) void wprep_all_kernel(
    const float* __restrict__ W0, const float* __restrict__ W1,
    const float* __restrict__ W2, const float* __restrict__ W3,
    const float* __restrict__ W4, const float* __restrict__ W5,
    const float* __restrict__ W6, unsigned short* __restrict__ wT) {
  const float* srcs[7] = {W0, W1, W2, W3, W4, W5, W6};
  int z = blockIdx.z, m = blockIdx.y;
  const float* W = srcs[z] + m*16384;
  unsigned short* WT = wT + z*32768 + m*16384;
  int t = blockIdx.x * 256 + threadIdx.x;
  int o = t >> 7, i = t & 127;
  WT[o*128 + i] = f2b(W[i*128 + o]);
}

// ---------------------------------------------------------------------------
// q / packed kv = x @ {Wq, Wk|Wv}. kv: u32 = {k lo16, v hi16} per (row,ch).
__global__ __launch_bounds__(256) void qkv_kernel(
    const float* __restrict__ x,
    const unsigned short* __restrict__ QT, const unsigned short* __restrict__ KT,
    const unsigned short* __restrict__ VT,
    unsigned short* __restrict__ qb, unsigned* __restrict__ kvb) {
  int w = threadIdx.x >> 6, l = threadIdx.x & 63;
  int lr = l & 15, lg = l >> 4;
  int R = blockIdx.x * 64 + w * 16;
  const float* xr = x + (size_t)(R + lr) * Dh + lg * 8;
  bf16x8 a[4];
  #pragma unroll
  for (int kt = 0; kt < 4; kt++) {
    bf16x8 av;
    #pragma unroll
    for (int j = 0; j < 8; j++) av[j] = (short)f2b(xr[kt*32 + j]);
    a[kt] = av;
  }
  #pragma unroll
  for (int n = 0; n < 8; n++) {
    f32x4 c = {0.f, 0.f, 0.f, 0.f};
    #pragma unroll
    for (int kt = 0; kt < 4; kt++)
      c = MFMA16(a[kt], *(const bf16x8*)&QT[(n*16 + lr)*Dh + kt*32 + lg*8], c);
    #pragma unroll
    for (int r = 0; r < 4; r++)
      qb[(size_t)(R + lg*4 + r)*Dh + n*16 + lr] = f2b(c[r]);
  }
  #pragma unroll
  for (int n = 0; n < 8; n++) {
    f32x4 ck = {0.f, 0.f, 0.f, 0.f}, cv = {0.f, 0.f, 0.f, 0.f};
    #pragma unroll
    for (int kt = 0; kt < 4; kt++) {
      ck = MFMA16(a[kt], *(const bf16x8*)&KT[(n*16 + lr)*Dh + kt*32 + lg*8], ck);
      cv = MFMA16(a[kt], *(const bf16x8*)&VT[(n*16 + lr)*Dh + kt*32 + lg*8], cv);
    }
    #pragma unroll
    for (int r = 0; r < 4; r++)
      kvb[(size_t)(R + lg*4 + r)*Dh + n*16 + lr] = pack_bf2(ck[r], cv[r]);
  }
}

// ---------------------------------------------------------------------------
// per-point prefetch context (registers only)
struct PtCtx {
  int jA, jC[4];
  float rx, ry, rz;
  unsigned short qv[8];
};
__device__ __forceinline__ void load_ctx(PtCtx& c, int p,
    const unsigned short* __restrict__ idxb, const float* __restrict__ pos,
    const unsigned short* __restrict__ qb, int lr, int lg) {
  c.jA = idxb[(size_t)p*KNN + lr];
  #pragma unroll
  for (int r = 0; r < 4; r++) c.jC[r] = idxb[(size_t)p*KNN + lg*4 + r];
  float px0 = pos[p*3+0], py0 = pos[p*3+1], pz0 = pos[p*3+2];
  c.rx = px0 - pos[c.jA*3+0];
  c.ry = py0 - pos[c.jA*3+1];
  c.rz = pz0 - pos[c.jA*3+2];
  #pragma unroll
  for (int n = 0; n < 8; n++) c.qv[n] = qb[(size_t)p*Dh + n*16 + lr];
}

// ---------------------------------------------------------------------------
// Mega fused vector-attention block. 256 blocks (1/CU) x 512 thr (8 waves).
// XCD-swizzled (batch b -> XCD b; kvb slice 2 MB fits 4 MB per-XCD L2).
// Register-pressure discipline (round-9 fix): kv burst regs die at the
// g-scatter, where v is folded into dlt in place (dlt becomes v+delta, used
// by softmax). nxt-ctx prefetch issues AFTER the scatter so phase-A and
// phase-C peaks are both ~110 regs < 128 (rounds 6-9 spilled ~18/point).
__global__ void __attribute__((amdgpu_flat_work_group_size(512, 512)))
__attribute__((amdgpu_waves_per_eu(2, 2)))
fused_mega_kernel(
    const unsigned short* __restrict__ qb, const unsigned* __restrict__ kvb,
    const unsigned short* __restrict__ idxb, const float* __restrict__ pos,
    const float* __restrict__ P1,
    const unsigned short* __restrict__ P2T, const unsigned short* __restrict__ G1T,
    const unsigned short* __restrict__ G2T, unsigned short* __restrict__ aggb) {
  __shared__ __align__(16) unsigned short wB[3][16384];    // 96 KB, swizzled
  __shared__ __align__(16) unsigned short trans[8][2048];  // 32 KB (4 KB/wave)
  int tid = threadIdx.x;
  int wv = tid >> 6, l = tid & 63;
  int lr = l & 15, lg = l >> 4;
  const int swz = (lr & 7) << 3;        // weight-LDS read swizzle (u16)
  const int swtR = swz16(lr);           // trans-tile read swizzle (row=lr)

  // XCD swizzle: hardware XCD = blockIdx.x % 8 -> batch b's 32 blocks on XCD b.
  int orig = (blockIdx.x & 7) * 32 + (blockIdx.x >> 3);

  {
    const unsigned short* srcs[3] = {P2T, G1T, G2T};
    #pragma unroll
    for (int z = 0; z < 3; z++) {
      const unsigned short* src = srcs[z];
      for (int t = tid * 8; t < 16384; t += 512 * 8) {
        int dst = t ^ (((t >> 7) & 7) << 3);
        *(u16x8*)&wB[z][dst] = *(const u16x8*)&src[t];
      }
    }
  }
  __syncthreads();

  unsigned short* tb = trans[wv];
  int p0 = orig * 128 + wv * 16;

  PtCtx cur, nxt;
  load_ctx(cur, p0, idxb, pos, qb, lr, lg);
  nxt = cur;

  #pragma unroll 1
  for (int i = 0; i < 16; i++) {
    int p = p0 + i;

    // ---- burst-issue all 32 packed kv gathers (consumed at g-scatter)
    const unsigned* kvp0 = kvb + (size_t)cur.jC[0]*Dh;
    const unsigned* kvp1 = kvb + (size_t)cur.jC[1]*Dh;
    const unsigned* kvp2 = kvb + (size_t)cur.jC[2]*Dh;
    const unsigned* kvp3 = kvb + (size_t)cur.jC[3]*Dh;
    unsigned kvr[8][4];
    #pragma unroll
    for (int n = 0; n < 8; n++) {
      kvr[n][0] = kvp0[n*16 + lr];
      kvr[n][1] = kvp1[n*16 + lr];
      kvr[n][2] = kvp2[n*16 + lr];
      kvr[n][3] = kvp3[n*16 + lr];
    }

    // ---- t1 = relu(rel @ P1) in A-frag layout; float4 P1 loads (L1-hot)
    bf16x8 aT[4];
    #pragma unroll
    for (int kt = 0; kt < 4; kt++) {
      int c0 = kt*32 + lg*8;
      float4 pa0 = *(const float4*)&P1[c0],        pa1 = *(const float4*)&P1[c0+4];
      float4 pb0 = *(const float4*)&P1[Dh+c0],     pb1 = *(const float4*)&P1[Dh+c0+4];
      float4 pc0 = *(const float4*)&P1[2*Dh+c0],   pc1 = *(const float4*)&P1[2*Dh+c0+4];
      bf16x8 av;
      av[0] = (short)f2b(fmaxf(cur.rx*pa0.x + cur.ry*pb0.x + cur.rz*pc0.x, 0.f));
      av[1] = (short)f2b(fmaxf(cur.rx*pa0.y + cur.ry*pb0.y + cur.rz*pc0.y, 0.f));
      av[2] = (short)f2b(fmaxf(cur.rx*pa0.z + cur.ry*pb0.z + cur.rz*pc0.z, 0.f));
      av[3] = (short)f2b(fmaxf(cur.rx*pa0.w + cur.ry*pb0.w + cur.rz*pc0.w, 0.f));
      av[4] = (short)f2b(fmaxf(cur.rx*pa1.x + cur.ry*pb1.x + cur.rz*pc1.x, 0.f));
      av[5] = (short)f2b(fmaxf(cur.rx*pa1.y + cur.ry*pb1.y + cur.rz*pc1.y, 0.f));
      av[6] = (short)f2b(fmaxf(cur.rx*pa1.z + cur.ry*pb1.z + cur.rz*pc1.z, 0.f));
      av[7] = (short)f2b(fmaxf(cur.rx*pa1.w + cur.ry*pb1.w + cur.rz*pc1.w, 0.f));
      aT[kt] = av;
    }

    // ---- DELTA = t1 @ P2 (C-layout regs, f32)
    f32x4 dlt[8];
    #pragma unroll
    for (int n = 0; n < 8; n++) {
      f32x4 c = {0.f, 0.f, 0.f, 0.f};
      #pragma unroll
      for (int kt = 0; kt < 4; kt++)
        c = MFMA16(aT[kt], *(const bf16x8*)&wB[0][((n*16 + lr)*Dh + kt*32 + lg*8) ^ swz], c);
      dlt[n] = c;
    }

    // ---- g = q - k + delta -> swizzled trans tile; fold v into dlt in place
    //      (dlt becomes v+delta; kvr dies here -> frees 32 regs for G1/G2)
    #pragma unroll
    for (int n = 0; n < 8; n++) {
      float q = b2f(cur.qv[n]);
      #pragma unroll
      for (int r = 0; r < 4; r++) {
        unsigned kv = kvr[n][r];
        int row = lg*4 + r, ch = n*16 + lr;
        tb[(row*Dh + ch) ^ swz16(row)] = f2b(q - blo(kv) + dlt[n][r]);
        dlt[n][r] += bhi(kv);
      }
    }

    // ---- prefetch next point's ctx (hidden under G1/G2/softmax)
    if (i < 15) load_ctx(nxt, p + 1, idxb, pos, qb, lr, lg);

    // ---- H = relu(g @ G1)
    bf16x8 ag[4];
    #pragma unroll
    for (int kt = 0; kt < 4; kt++)
      ag[kt] = *(const bf16x8*)&tb[(lr*Dh + kt*32 + lg*8) ^ swtR];
    f32x4 hh[8];
    #pragma unroll
    for (int n = 0; n < 8; n++) {
      f32x4 c = {0.f, 0.f, 0.f, 0.f};
      #pragma unroll
      for (int kt = 0; kt < 4; kt++)
        c = MFMA16(ag[kt], *(const bf16x8*)&wB[1][((n*16 + lr)*Dh + kt*32 + lg*8) ^ swz], c);
      hh[n] = c;
    }
    #pragma unroll
    for (int n = 0; n < 8; n++) {
      #pragma unroll
      for (int r = 0; r < 4; r++) {
        int row = lg*4 + r, ch = n*16 + lr;
        tb[(row*Dh + ch) ^ swz16(row)] = f2b(fmaxf(hh[n][r], 0.f));
      }
    }

    // ---- LOGITS = H @ G2
    bf16x8 ah[4];
    #pragma unroll
    for (int kt = 0; kt < 4; kt++)
      ah[kt] = *(const bf16x8*)&tb[(lr*Dh + kt*32 + lg*8) ^ swtR];
    f32x4 lgt[8];
    #pragma unroll
    for (int n = 0; n < 8; n++) {
      f32x4 c = {0.f, 0.f, 0.f, 0.f};
      #pragma unroll
      for (int kt = 0; kt < 4; kt++)
        c = MFMA16(ah[kt], *(const bf16x8*)&wB[2][((n*16 + lr)*Dh + kt*32 + lg*8) ^ swz], c);
      lgt[n] = c;
    }

    // ---- softmax over 16 neighbors + agg = sum attn*(v+delta)  [dlt = v+delta]
    #pragma unroll
    for (int n = 0; n < 8; n++) {
      f32x4 L = lgt[n];
      float m = fmaxf(fmaxf(L[0], L[1]), fmaxf(L[2], L[3]));
      m = fmaxf(m, __shfl_xor(m, 16));
      m = fmaxf(m, __shfl_xor(m, 32));
      float e0 = __expf(L[0]-m), e1 = __expf(L[1]-m);
      float e2 = __expf(L[2]-m), e3 = __expf(L[3]-m);
      float s = e0 + e1 + e2 + e3;
      s += __shfl_xor(s, 16);
      s += __shfl_xor(s, 32);
      float inv = 1.f / s;
      float ws;
      ws  = e0 * dlt[n][0];
      ws += e1 * dlt[n][1];
      ws += e2 * dlt[n][2];
      ws += e3 * dlt[n][3];
      ws *= inv;
      ws += __shfl_xor(ws, 16);
      ws += __shfl_xor(ws, 32);
      if (lg == 0) aggb[(size_t)p*Dh + n*16 + lr] = f2b(ws);
    }

    cur = nxt;
  }
}

// ---------------------------------------------------------------------------
// x += aggb @ Wo : [32768,128]@[128,128], f32 accumulate into x.
__global__ __launch_bounds__(256) void xupd_kernel(
    float* __restrict__ x, const unsigned short* __restrict__ aggb,
    const unsigned short* __restrict__ WoT) {
  int w = threadIdx.x >> 6, l = threadIdx.x & 63;
  int lr = l & 15, lg = l >> 4;
  int R = blockIdx.x * 64 + w * 16;
  bf16x8 a[4];
  #pragma unroll
  for (int kt = 0; kt < 4; kt++)
    a[kt] = *(const bf16x8*)&aggb[(size_t)(R + lr)*Dh + kt*32 + lg*8];
  #pragma unroll
  for (int n = 0; n < 8; n++) {
    f32x4 c = {0.f, 0.f, 0.f, 0.f};
    #pragma unroll
    for (int kt = 0; kt < 4; kt++)
      c = MFMA16(a[kt], *(const bf16x8*)&WoT[(n*16 + lr)*Dh + kt*32 + lg*8], c);
    #pragma unroll
    for (int r = 0; r < 4; r++)
      x[(size_t)(R + lg*4 + r)*Dh + n*16 + lr] += c[r];
  }
}

// ---------------------------------------------------------------------------
// Global max-pool + classifier head (f32)
__global__ __launch_bounds__(128) void pool_part_kernel(
    const float* __restrict__ x, float* __restrict__ part) {
  int b = blockIdx.y, chunk = blockIdx.x, d = threadIdx.x;
  const float* xb = x + ((size_t)b*NN + chunk*128) * Dh;
  float m = -FLT_MAX;
  for (int n = 0; n < 128; n++) m = fmaxf(m, xb[(size_t)n*Dh + d]);
  part[(b*32 + chunk)*Dh + d] = m;
}

__global__ __launch_bounds__(128) void head_kernel(
    const float* __restrict__ part, const float* __restrict__ W1,
    const float* __restrict__ W2, float* __restrict__ out) {
  int b = blockIdx.x, d = threadIdx.x;
  __shared__ float pooled[Dh], h[Dh];
  float m = -FLT_MAX;
  for (int c = 0; c < 32; c++) m = fmaxf(m, part[(b*32 + c)*Dh + d]);
  pooled[d] = m;
  __syncthreads();
  float acc = 0.f;
  for (int c = 0; c < Dh; c++) acc += pooled[c] * W1[c*Dh + d];
  h[d] = fmaxf(acc, 0.f);
  __syncthreads();
  if (d < 40) {
    float o = 0.f;
    for (int c = 0; c < Dh; c++) o += h[c] * W2[c*40 + d];
    out[b*40 + d] = o;
  }
}

// ---------------------------------------------------------------------------
extern "C" void kernel_launch(void* const* d_in, const int* in_sizes, int n_in,
                              void* d_out, int out_size, void* d_ws, size_t ws_size,
                              hipStream_t stream) {
  const float* features = (const float*)d_in[0];
  const float* pos      = (const float*)d_in[1];
  const float* W_embed  = (const float*)d_in[2];
  const float* Wq       = (const float*)d_in[3];
  const float* Wk       = (const float*)d_in[4];
  const float* Wv       = (const float*)d_in[5];
  const float* P1       = (const float*)d_in[6];
  const float* P2       = (const float*)d_in[7];
  const float* G1       = (const float*)d_in[8];
  const float* G2       = (const float*)d_in[9];
  const float* Wo       = (const float*)d_in[10];
  const float* Wc1      = (const float*)d_in[11];
  const float* Wc2      = (const float*)d_in[12];
  float* out = (float*)d_out;

  // workspace layout (16B-aligned slices)
  float* x = (float*)d_ws;                                     // NPTS*Dh f32 (16 MB)
  unsigned short* qb = (unsigned short*)(x + (size_t)NPTS*Dh); // NPTS*Dh bf16 (8 MB)
  unsigned* kvb = (unsigned*)(qb + (size_t)NPTS*Dh);           // NPTS*Dh u32 (16 MB)
  unsigned short* wT = (unsigned short*)(kvb + (size_t)NPTS*Dh); // 7*2*16384 bf16
  unsigned short* aggb = wT + 7*2*16384;                       // NPTS*Dh bf16 (8 MB)
  unsigned short* idxb = aggb + (size_t)NPTS*Dh;               // NPTS*KNN u16 (1 MB)

  // kNN partial indices (u16): aliased onto kvb (needs 8.4 MB of 16); dead before qkv.
  unsigned short* pidx = (unsigned short*)kvb;
  // pooled partials: aliased onto qb (dead after last fused layer).
  float* part = (float*)qb;

  unsigned short* QT  = wT + 0*32768;   // [2][128][128] each, transposed bf16
  unsigned short* KT  = wT + 1*32768;
  unsigned short* VT  = wT + 2*32768;
  unsigned short* P2T = wT + 3*32768;
  unsigned short* G1T = wT + 4*32768;
  unsigned short* G2T = wT + 5*32768;
  unsigned short* WoT = wT + 6*32768;

  knn_part_kernel<<<dim3(NN/256, NPART, BB), 256, 0, stream>>>(pos, pidx);
  knn_merge_kernel<<<NPTS/256, 256, 0, stream>>>(pos, pidx, idxb);

  wprep_all_kernel<<<dim3(64, 2, 7), 256, 0, stream>>>(Wq, Wk, Wv, P2, G1, G2, Wo, wT);
  embed_kernel<<<NPTS*Dh/256, 256, 0, stream>>>(features, W_embed, x);

  for (int l = 0; l < 2; l++) {
    qkv_kernel<<<NPTS/64, 256, 0, stream>>>(
        x, QT + l*16384, KT + l*16384, VT + l*16384, qb, kvb);
    fused_mega_kernel<<<256, 512, 0, stream>>>(
        qb, kvb, idxb, pos,
        P1 + l*3*Dh, P2T + l*16384, G1T + l*16384, G2T + l*16384, aggb);
    xupd_kernel<<<NPTS/64, 256, 0, stream>>>(x, aggb, WoT + l*16384);
  }

  pool_part_kernel<<<dim3(32, BB), 128, 0, stream>>>(x, part);
  head_kernel<<<BB, 128, 0, stream>>>(part, Wc1, Wc2, out);
}